// Round 4
// baseline (408.493 us; speedup 1.0000x reference)
//
#include <hip/hip_runtime.h>
#include <hip/hip_bf16.h>

// Problem constants (B,R,M,L,H) = (256, 2048, 65536, 64, 4)
#define BB   256
#define RR   2048
#define MM   65536
#define LL   64
#define HH   4
#define NROW 1024      // B*H rows
#define KEYS 256       // H*L

typedef float f32x4 __attribute__((ext_vector_type(4)));
typedef short short8 __attribute__((ext_vector_type(8)));

#define MFMA(A,B,C) __builtin_amdgcn_mfma_f32_16x16x32_bf16((A),(B),(C),0,0,0)

// ---- bf16 round-nearest-even split helpers ----
__device__ __forceinline__ unsigned short bf16_rn(float x) {
    union { float f; unsigned int u; } v; v.f = x;
    unsigned int r = v.u + 0x7FFFu + ((v.u >> 16) & 1u);
    return (unsigned short)(r >> 16);
}
__device__ __forceinline__ float bf16_to_f(unsigned short h) {
    union { float f; unsigned int u; } v; v.u = ((unsigned int)h) << 16; return v.f;
}
__device__ __forceinline__ void split8_store(const float* x, unsigned short* hi, unsigned short* lo) {
    unsigned int ph[4], pl[4];
#pragma unroll
    for (int j = 0; j < 4; ++j) {
        unsigned short h0 = bf16_rn(x[2*j]),   l0 = bf16_rn(x[2*j]   - bf16_to_f(h0));
        unsigned short h1 = bf16_rn(x[2*j+1]), l1 = bf16_rn(x[2*j+1] - bf16_to_f(h1));
        ph[j] = (unsigned int)h0 | ((unsigned int)h1 << 16);
        pl[j] = (unsigned int)l0 | ((unsigned int)l1 << 16);
    }
    ((uint4*)hi)[0] = make_uint4(ph[0], ph[1], ph[2], ph[3]);
    ((uint4*)lo)[0] = make_uint4(pl[0], pl[1], pl[2], pl[3]);
}

// ---- fused prep: blocks [0,2048) = mem->B-fragments + per-block row-norm max;
//      blocks [2048,2176) = Wk 64x64 transpose tiles ----
__global__ __launch_bounds__(256) void prep_fused(const float* __restrict__ mem,
                                                  const float* __restrict__ Wk,
                                                  unsigned short* __restrict__ bhi,
                                                  unsigned short* __restrict__ blo,
                                                  float* __restrict__ normpart,
                                                  float* __restrict__ WkT) {
    int blk = blockIdx.x;
    int tid = threadIdx.x;
    if (blk < 2048) {
        __shared__ float cs[64];               // [wave][row] chunk sums
        int gid = blk * 256 + tid;             // 0..524287
        int lane = gid & 63, frag = gid >> 6;  // frag 0..8191 ; frag = t*2 + c
        int t = frag >> 1, c = frag & 1;
        int mrow = t * 16 + (lane & 15);
        int k0 = c * 32 + (lane >> 4) * 8;
        const float4* src = (const float4*)(mem + (size_t)mrow * LL + k0);
        float4 x0 = src[0], x1 = src[1];
        float x[8] = {x0.x, x0.y, x0.z, x0.w, x1.x, x1.y, x1.z, x1.w};
        split8_store(x, bhi + (size_t)gid * 8, blo + (size_t)gid * 8);
        float sq = 0.f;
#pragma unroll
        for (int j = 0; j < 8; ++j) sq += x[j] * x[j];
        sq += __shfl_xor(sq, 16, 64);
        sq += __shfl_xor(sq, 32, 64);          // per-row sum over this 32-wide K chunk
        int w = tid >> 6;
        if (lane < 16) cs[w * 16 + lane] = sq;
        __syncthreads();
        if (tid < 32) {
            int tt = tid >> 4, rr = tid & 15;
            float s = cs[(tt * 2) * 16 + rr] + cs[(tt * 2 + 1) * 16 + rr]; // full row norm^2
#pragma unroll
            for (int off = 1; off < 32; off <<= 1) s = fmaxf(s, __shfl_xor(s, off, 64));
            if (tid == 0) normpart[blk] = s;
        }
    } else {
        __shared__ float tbuf[64 * 65];
        int tx = blk - 2048;                   // 0..127 : (4 x 32) tiles
        int r0 = (tx & 3) * 64, c0 = (tx >> 2) * 64;
        int lane = tid & 63, w = tid >> 6;
#pragma unroll
        for (int i = 0; i < 16; ++i) {
            int rr = i * 4 + w;
            tbuf[lane * 65 + rr] = Wk[(size_t)(r0 + rr) * RR + c0 + lane];
        }
        __syncthreads();
#pragma unroll
        for (int i = 0; i < 16; ++i) {
            int cc = i * 4 + w;
            WkT[(size_t)(c0 + cc) * KEYS + r0 + lane] = tbuf[cc * 65 + lane];
        }
    }
}

// ---------------- K0: split-k partial keys GEMM ----------------
__global__ __launch_bounds__(256) void k0_keys(const float* __restrict__ S,
                                               const float* __restrict__ WkT,
                                               float* __restrict__ kpart) {
    __shared__ float sl[8 * 256];
    int bg = blockIdx.x, kc = blockIdx.y, tid = threadIdx.x;
    int b0 = bg * 8;
#pragma unroll
    for (int bi = 0; bi < 8; ++bi)
        sl[bi * 256 + tid] = S[(size_t)(b0 + bi) * RR + kc * 256 + tid];
    __syncthreads();
    float acc[8] = {0,0,0,0,0,0,0,0};
    const float* wp = WkT + (size_t)kc * 256 * KEYS + tid;
#pragma unroll 4
    for (int kk = 0; kk < 256; ++kk) {
        float wv = wp[kk * KEYS];
#pragma unroll
        for (int bi = 0; bi < 8; ++bi)
            acc[bi] = fmaf(sl[bi * 256 + kk], wv, acc[bi]);
    }
    float* op = kpart + (size_t)kc * BB * KEYS + (size_t)b0 * KEYS + tid;
#pragma unroll
    for (int bi = 0; bi < 8; ++bi)
        op[bi * KEYS] = acc[bi];
}

// ---------------- K1: beta, key norm, q_rm, brow = beta*maxnorm ----------------
__global__ __launch_bounds__(256) void k1_finalize(const float* __restrict__ S,
                                                   const float* __restrict__ kpart,
                                                   const float* __restrict__ bk,
                                                   const float* __restrict__ Wb,
                                                   const float* __restrict__ bb,
                                                   const float* __restrict__ normpart,
                                                   float* __restrict__ q_rm,
                                                   float* __restrict__ brow) {
    int bh = blockIdx.x, b = bh >> 2, h = bh & 3;
    int tid = threadIdx.x, lane = tid & 63, w = tid >> 6;
    float p = 0.f;
#pragma unroll
    for (int i = 0; i < 8; ++i) {
        int k = i * 256 + tid;
        p += S[(size_t)b * RR + k] * Wb[(size_t)h * RR + k];
    }
    float nm = 0.f;
#pragma unroll
    for (int i = 0; i < 8; ++i) nm = fmaxf(nm, normpart[i * 256 + tid]);
#pragma unroll
    for (int off = 1; off < 64; off <<= 1) {
        p  += __shfl_xor(p, off, 64);
        nm  = fmaxf(nm, __shfl_xor(nm, off, 64));
    }
    __shared__ float red[4], redm[4];
    if (lane == 0) { red[w] = p; redm[w] = nm; }
    __syncthreads();
    if (tid < 64) {
        float beta = red[0] + red[1] + red[2] + red[3] + bb[h];
        beta = fmaxf(beta, 0.f);
        float maxn = sqrtf(fmaxf(fmaxf(redm[0], redm[1]), fmaxf(redm[2], redm[3])));
        float kv = bk[h * LL + lane];
#pragma unroll
        for (int c = 0; c < 8; ++c)
            kv += kpart[(size_t)c * BB * KEYS + (size_t)b * KEYS + h * LL + lane];
        float sq = kv * kv;
#pragma unroll
        for (int off = 1; off < 64; off <<= 1) sq += __shfl_xor(sq, off, 64);
        float scale = beta / sqrtf(sq);
        q_rm[(size_t)bh * LL + lane] = kv * scale;
        if (lane == 0) brow[bh] = beta * maxn;   // Cauchy-Schwarz upper bound on dot
    }
}

// ---------------- swizzle q into MFMA A-fragment order, hi/lo bf16 ----------------
__global__ __launch_bounds__(256) void prep_a(const float* __restrict__ q_rm,
                                              unsigned short* __restrict__ ahi,
                                              unsigned short* __restrict__ alo) {
    int gid = blockIdx.x * 256 + threadIdx.x;   // 0..8191
    int lane = gid & 63, frag = gid >> 6;       // frag 0..127 = rtg*2 + c
    int rtg = frag >> 1, c = frag & 1;
    int row = rtg * 16 + (lane & 15);
    int k0 = c * 32 + (lane >> 4) * 8;
    const float4* src = (const float4*)(q_rm + (size_t)row * LL + k0);
    float4 x0 = src[0], x1 = src[1];
    float x[8] = {x0.x, x0.y, x0.z, x0.w, x1.x, x1.y, x1.z, x1.w};
    split8_store(x, ahi + (size_t)gid * 8, alo + (size_t)gid * 8);
}

// ---- XCD-aware decode: all 16 rg blocks of one mblk land on the same XCD (bx%8) ----
__device__ __forceinline__ void decode_bx(int bx, int& mblk, int& rg) {
    int xcd = bx & 7;
    int tmp = bx >> 3;
    rg = tmp & 15;
    mblk = (tmp >> 4) * 8 + xcd;
}

// ---------------- K2: split-bf16 MFMA dot + exp(d - brow) partial row sums ----------
__global__ __launch_bounds__(256) void k2_mfma(const unsigned short* __restrict__ bhi,
                                               const unsigned short* __restrict__ blo,
                                               const unsigned short* __restrict__ ahi,
                                               const unsigned short* __restrict__ alo,
                                               const float* __restrict__ brow,
                                               float* __restrict__ psum) {
    int mblk, rg; decode_bx(blockIdx.x, mblk, rg);
    int tid = threadIdx.x, w = tid >> 6, lane = tid & 63;
    int g = lane >> 4;
    short8 Ah[4][2], Al[4][2];
#pragma unroll
    for (int rt = 0; rt < 4; ++rt)
#pragma unroll
        for (int c = 0; c < 2; ++c) {
            size_t off = ((size_t)((rg * 4 + rt) * 2 + c) * 64 + lane) * 8;
            Ah[rt][c] = *(const short8*)(ahi + off);
            Al[rt][c] = *(const short8*)(alo + off);
        }
    float br[4][4];
#pragma unroll
    for (int rt = 0; rt < 4; ++rt)
#pragma unroll
        for (int r = 0; r < 4; ++r)
            br[rt][r] = brow[rg * 64 + rt * 16 + g * 4 + r];
    float s[4][4] = {{0.f}};
    int t0 = mblk * 64 + w * 16;
#pragma unroll 2
    for (int ti = 0; ti < 16; ++ti) {
        int t = t0 + ti;
        size_t o0 = ((size_t)(t * 2 + 0) * 64 + lane) * 8;
        size_t o1 = ((size_t)(t * 2 + 1) * 64 + lane) * 8;
        short8 Bh0 = *(const short8*)(bhi + o0);
        short8 Bh1 = *(const short8*)(bhi + o1);
        short8 Bl0 = *(const short8*)(blo + o0);
        short8 Bl1 = *(const short8*)(blo + o1);
#pragma unroll
        for (int rt = 0; rt < 4; ++rt) {
            f32x4 C = {0.f, 0.f, 0.f, 0.f};
            C = MFMA(Ah[rt][0], Bh0, C);
            C = MFMA(Ah[rt][1], Bh1, C);
            C = MFMA(Al[rt][0], Bh0, C);
            C = MFMA(Al[rt][1], Bh1, C);
            C = MFMA(Ah[rt][0], Bl0, C);
            C = MFMA(Ah[rt][1], Bl1, C);
#pragma unroll
            for (int r = 0; r < 4; ++r)
                s[rt][r] += __expf(C[r] - br[rt][r]);
        }
    }
#pragma unroll
    for (int rt = 0; rt < 4; ++rt)
#pragma unroll
        for (int r = 0; r < 4; ++r) {
            float v = s[rt][r];
            v += __shfl_xor(v, 1, 64);
            v += __shfl_xor(v, 2, 64);
            v += __shfl_xor(v, 4, 64);
            v += __shfl_xor(v, 8, 64);
            s[rt][r] = v;
        }
    if ((lane & 15) == 0) {
        int col = mblk * 4 + w;
#pragma unroll
        for (int rt = 0; rt < 4; ++rt)
#pragma unroll
            for (int r = 0; r < 4; ++r) {
                int row = rg * 64 + rt * 16 + g * 4 + r;
                psum[(size_t)row * 256 + col] = s[rt][r];
            }
    }
}

// ---------------- K3: combine 256 partial sums per row -> 1/sum ----------------
__global__ __launch_bounds__(256) void k3_combine(const float* __restrict__ psum,
                                                  float* __restrict__ ginv) {
    int row = blockIdx.x, tid = threadIdx.x, lane = tid & 63, w = tid >> 6;
    float v = psum[(size_t)row * 256 + tid];
#pragma unroll
    for (int off = 1; off < 64; off <<= 1) v += __shfl_xor(v, off, 64);
    __shared__ float sm[4];
    if (lane == 0) sm[w] = v;
    __syncthreads();
    if (tid == 0) ginv[row] = 1.0f / (sm[0] + sm[1] + sm[2] + sm[3]);
}

// ---------------- K4: recompute dots via MFMA, write exp(d-brow)*ginv ----------------
__global__ __launch_bounds__(256) void k4_mfma(const unsigned short* __restrict__ bhi,
                                               const unsigned short* __restrict__ blo,
                                               const unsigned short* __restrict__ ahi,
                                               const unsigned short* __restrict__ alo,
                                               const float* __restrict__ brow,
                                               const float* __restrict__ ginv,
                                               float* __restrict__ out) {
    int mblk, rg; decode_bx(blockIdx.x, mblk, rg);
    int tid = threadIdx.x, w = tid >> 6, lane = tid & 63;
    int g = lane >> 4;
    short8 Ah[4][2], Al[4][2];
#pragma unroll
    for (int rt = 0; rt < 4; ++rt)
#pragma unroll
        for (int c = 0; c < 2; ++c) {
            size_t off = ((size_t)((rg * 4 + rt) * 2 + c) * 64 + lane) * 8;
            Ah[rt][c] = *(const short8*)(ahi + off);
            Al[rt][c] = *(const short8*)(alo + off);
        }
    float br[4][4], gv[4][4];
    size_t rbase[4][4];
#pragma unroll
    for (int rt = 0; rt < 4; ++rt)
#pragma unroll
        for (int r = 0; r < 4; ++r) {
            int row = rg * 64 + rt * 16 + g * 4 + r;
            br[rt][r] = brow[row];
            gv[rt][r] = ginv[row];
            rbase[rt][r] = (size_t)row * MM + (lane & 15);
        }
    int t0 = mblk * 64 + w * 16;
#pragma unroll 2
    for (int ti = 0; ti < 16; ++ti) {
        int t = t0 + ti;
        size_t o0 = ((size_t)(t * 2 + 0) * 64 + lane) * 8;
        size_t o1 = ((size_t)(t * 2 + 1) * 64 + lane) * 8;
        short8 Bh0 = *(const short8*)(bhi + o0);
        short8 Bh1 = *(const short8*)(bhi + o1);
        short8 Bl0 = *(const short8*)(blo + o0);
        short8 Bl1 = *(const short8*)(blo + o1);
#pragma unroll
        for (int rt = 0; rt < 4; ++rt) {
            f32x4 C = {0.f, 0.f, 0.f, 0.f};
            C = MFMA(Ah[rt][0], Bh0, C);
            C = MFMA(Ah[rt][1], Bh1, C);
            C = MFMA(Al[rt][0], Bh0, C);
            C = MFMA(Al[rt][1], Bh1, C);
            C = MFMA(Ah[rt][0], Bl0, C);
            C = MFMA(Ah[rt][1], Bl1, C);
#pragma unroll
            for (int r = 0; r < 4; ++r) {
                float o = __expf(C[r] - br[rt][r]) * gv[rt][r];
                __builtin_nontemporal_store(o, out + rbase[rt][r] + (size_t)t * 16);
            }
        }
    }
}

extern "C" void kernel_launch(void* const* d_in, const int* in_sizes, int n_in,
                              void* d_out, int out_size, void* d_ws, size_t ws_size,
                              hipStream_t stream) {
    const float* S   = (const float*)d_in[0];  // [256][2048]
    const float* mem = (const float*)d_in[1];  // [65536][64]
    const float* Wk  = (const float*)d_in[2];  // [256][2048]
    const float* bk  = (const float*)d_in[3];  // [256]
    const float* Wb  = (const float*)d_in[4];  // [4][2048]
    const float* bb  = (const float*)d_in[5];  // [4]
    float* out = (float*)d_out;                // [1024][65536]

    // workspace layout (~21.5 MB, all segments 16B-aligned)
    float* WkT      = (float*)d_ws;                          // 2048*256
    float* kpart    = WkT   + (size_t)RR * KEYS;             // 8*256*256
    float* q_rm     = kpart + (size_t)8 * BB * KEYS;         // 1024*64
    float* psum     = q_rm  + (size_t)NROW * LL;             // 1024*256
    float* brow     = psum  + (size_t)NROW * 256;            // 1024
    float* ginv     = brow  + NROW;                          // 1024
    float* normpart = ginv  + NROW;                          // 2048
    unsigned short* bhi = (unsigned short*)(normpart + 2048);// 8192*512
    unsigned short* blo = bhi + (size_t)8192 * 512;
    unsigned short* ahi = blo + (size_t)8192 * 512;          // 128*512
    unsigned short* alo = ahi + (size_t)128 * 512;

    prep_fused <<<2176,        256, 0, stream>>>(mem, Wk, bhi, blo, normpart, WkT);
    k0_keys    <<<dim3(32, 8), 256, 0, stream>>>(S, WkT, kpart);
    k1_finalize<<<NROW,        256, 0, stream>>>(S, kpart, bk, Wb, bb, normpart, q_rm, brow);
    prep_a     <<<32,          256, 0, stream>>>(q_rm, ahi, alo);
    k2_mfma    <<<1024,        256, 0, stream>>>(bhi, blo, ahi, alo, brow, psum);
    k3_combine <<<NROW,        256, 0, stream>>>(psum, ginv);
    k4_mfma    <<<1024,        256, 0, stream>>>(bhi, blo, ahi, alo, brow, ginv, out);
}